// Round 4
// baseline (2999.524 us; speedup 1.0000x reference)
//
#include <hip/hip_runtime.h>
#include <hip/hip_bf16.h>

#define NATOM 100000
#define MNBR  12
#define FDIM  64
#define BDIM  41
#define C2    128
#define EPSBN 1e-5f
#define NEDGE (NATOM * MNBR)   // 1,200,000
#define KP    64               // nbr K padded for MFMA (41 -> 64)
#define KALL  192              // x[n] (64) | x[j] (64) | nbr (64)
#define PLD   68               // p_s row stride (f32)

typedef __attribute__((ext_vector_type(8))) short bf16x8;
typedef __attribute__((ext_vector_type(4))) float f32x4;

// ---- ws layout (float units) ----
#define X_OFF    0L            // x: N*64 f32 (master)
#define XB_OFF   6400000L      // xb: N*64 bf16
#define S_OFF    9600000L      // nbr_sumed: N*64 f32
#define NBRB_OFF 16000000L     // nbr bf16 padded: 1.2M*64 bf16
#define BALL_OFF 54400000L     // B_all^T bf16: 128 cols * 192 k
#define BN1S_OFF 54412288L     // 64 slots * 256
#define BN2S_OFF 54428672L     // 64 slots * 128
#define SC1_OFF  54436864L
#define SH1_OFF  54436992L
#define SC2_OFF  54437120L
#define SH2_OFF  54437184L
#define CRY_OFF  54437248L     // 2000*64
#define CNT_OFF  54565248L     // 2000
#define ZERO_OFF BN1S_OFF
#define ZERO_CNT 154960L

__device__ __forceinline__ float softplus_f(float v) {
    return fmaxf(v, 0.f) + __logf(1.f + __expf(-fabsf(v)));
}

__global__ void k_zero(float* __restrict__ p, long cnt) {
    long i = (long)blockIdx.x * 256 + threadIdx.x;
    if (i < cnt) p[i] = 0.f;
}

// nbr_fea f32 [1.2M][41] -> bf16 [1.2M][64] zero-padded
__global__ void k_nbrcvt(const float* __restrict__ nbr, __hip_bfloat16* __restrict__ outb) {
    long i = (long)blockIdx.x * 256 + threadIdx.x;
    if (i >= (long)NEDGE * KP) return;
    long e = i >> 6;
    int k = (int)(i & 63);
    float v = (k < BDIM) ? nbr[e * BDIM + k] : 0.f;
    outb[i] = __float2bfloat16(v);
}

// B_all^T bf16 [128 cols][192 k]: k<128 -> conv_w rows 0..127 (self|nbr), 128..168 -> bond, pad 0
__global__ void k_bcvt(const float* __restrict__ cw, __hip_bfloat16* __restrict__ ball) {
    int i = blockIdx.x * 256 + threadIdx.x;   // < 24576
    if (i >= 128 * KALL) return;
    int c = i / KALL, k = i - c * KALL;
    float v = (k < 169) ? cw[k * C2 + c] : 0.f;
    ball[i] = __float2bfloat16(v);
}

__global__ __launch_bounds__(256)
void k_embed(const float* __restrict__ af, const float* __restrict__ ew,
             const float* __restrict__ eb, float* __restrict__ x,
             __hip_bfloat16* __restrict__ xb) {
    int t = threadIdx.x;
    int c = t & 63, ag = t >> 6;
    long n0 = (long)blockIdx.x * 16 + ag * 4;
    float acc[4] = {0.f, 0.f, 0.f, 0.f};
    for (int k4 = 0; k4 < 23; ++k4) {
        float w0 = ew[(4 * k4 + 0) * FDIM + c];
        float w1 = ew[(4 * k4 + 1) * FDIM + c];
        float w2 = ew[(4 * k4 + 2) * FDIM + c];
        float w3 = ew[(4 * k4 + 3) * FDIM + c];
#pragma unroll
        for (int a = 0; a < 4; ++a) {
            const float4* ar = (const float4*)(af + (n0 + a) * 92);
            float4 v = ar[k4];
            acc[a] += v.x * w0 + v.y * w1 + v.z * w2 + v.w * w3;
        }
    }
    float b = eb[c];
#pragma unroll
    for (int a = 0; a < 4; ++a) {
        float v = acc[a] + b;
        x[(n0 + a) * FDIM + c] = v;
        xb[(n0 + a) * FDIM + c] = __float2bfloat16(v);
    }
}

// Edge kernel: one K=192 MFMA GEMM per 16-edge tile, A gathered per-lane from
// global (xb[n] | xb[j] | nbrb[e]); no LDS staging, no elementwise gather-add.
// APPLY=0: BN1 column stats (no bias; folded in k_bnfin).
// APPLY=1: BN1 apply + sigmoid*softplus in-register, p->LDS, m-sum->sout, BN2 stats.
template <int APPLY>
__global__ __launch_bounds__(192, 4)
void k_edge(const __hip_bfloat16* __restrict__ xb,
            const __hip_bfloat16* __restrict__ nbrb,
            const __hip_bfloat16* __restrict__ ball,
            const int* __restrict__ idxp,
            const float* __restrict__ sc1, const float* __restrict__ sh1,
            float* __restrict__ bn1_slots,
            float* __restrict__ sout, float* __restrict__ bn2_slots) {
    __shared__ float p_s[48 * PLD];    // apply only (13056 B)
    __shared__ float bn_s[256];
    __shared__ float sc_s[128], sh_s[128];

    const int t = threadIdx.x;
    const int w = t >> 6, l = t & 63;
    const int lo = l & 15, hi = l >> 4;
    const long n0 = (long)blockIdx.x * 4;
    const long e0 = n0 * MNBR;   // 48 edges

    for (int o = t; o < 256; o += 192) bn_s[o] = 0.f;
    if (APPLY && t < 128) { sc_s[t] = sc1[t]; sh_s[t] = sh1[t]; }
    __syncthreads();

    // per-lane A-row: edge e_ld (row index lo of this wave's 16-edge tile)
    const long e_ld = e0 + w * 16 + lo;
    const int n_ld = (int)(e_ld / 12);
    const int j_ld = idxp[e_ld];
    const short* xn = (const short*)xb + (long)n_ld * FDIM + hi * 8;
    const short* xj = (const short*)xb + (long)j_ld * FDIM + hi * 8;
    const short* nb = (const short*)nbrb + e_ld * KP + hi * 8;

    bf16x8 A0 = *(const bf16x8*)(xn);
    bf16x8 A1 = *(const bf16x8*)(xn + 32);
    bf16x8 A2 = *(const bf16x8*)(xj);
    bf16x8 A3 = *(const bf16x8*)(xj + 32);
    bf16x8 A4 = *(const bf16x8*)(nb);
    bf16x8 A5 = *(const bf16x8*)(nb + 32);

    f32x4 acc[8];
#pragma unroll
    for (int T = 0; T < 8; ++T) {
        const short* Bb = (const short*)ball + (T * 16 + lo) * KALL + hi * 8;
        bf16x8 B0 = *(const bf16x8*)(Bb);
        bf16x8 B1 = *(const bf16x8*)(Bb + 32);
        bf16x8 B2 = *(const bf16x8*)(Bb + 64);
        bf16x8 B3 = *(const bf16x8*)(Bb + 96);
        bf16x8 B4 = *(const bf16x8*)(Bb + 128);
        bf16x8 B5 = *(const bf16x8*)(Bb + 160);
        f32x4 z = {0.f, 0.f, 0.f, 0.f};
        z = __builtin_amdgcn_mfma_f32_16x16x32_bf16(A0, B0, z, 0, 0, 0);
        z = __builtin_amdgcn_mfma_f32_16x16x32_bf16(A1, B1, z, 0, 0, 0);
        z = __builtin_amdgcn_mfma_f32_16x16x32_bf16(A2, B2, z, 0, 0, 0);
        z = __builtin_amdgcn_mfma_f32_16x16x32_bf16(A3, B3, z, 0, 0, 0);
        z = __builtin_amdgcn_mfma_f32_16x16x32_bf16(A4, B4, z, 0, 0, 0);
        acc[T] = __builtin_amdgcn_mfma_f32_16x16x32_bf16(A5, B5, z, 0, 0, 0);
    }
    // output: col = T*16+lo, edge = w*16 + hi*4 + qq

    if (APPLY == 0) {
#pragma unroll
        for (int T = 0; T < 8; ++T) {
            float s1 = acc[T][0] + acc[T][1] + acc[T][2] + acc[T][3];
            float s2 = acc[T][0] * acc[T][0] + acc[T][1] * acc[T][1] +
                       acc[T][2] * acc[T][2] + acc[T][3] * acc[T][3];
            s1 += __shfl_xor(s1, 16); s2 += __shfl_xor(s2, 16);
            s1 += __shfl_xor(s1, 32); s2 += __shfl_xor(s2, 32);
            if (hi == 0) {
                atomicAdd(&bn_s[T * 16 + lo], s1);
                atomicAdd(&bn_s[128 + T * 16 + lo], s2);
            }
        }
        __syncthreads();
        for (int o = t; o < 256; o += 192)
            atomicAdd(&bn1_slots[(blockIdx.x & 63) * 256 + o], bn_s[o]);
    } else {
        const int ebase = w * 16 + hi * 4;
        float pv[4][4];
#pragma unroll
        for (int T = 0; T < 4; ++T) {
            const int c = T * 16 + lo;
            const float s_f = sc_s[c], h_f = sh_s[c];
            const float s_c = sc_s[64 + c], h_c = sh_s[64 + c];
#pragma unroll
            for (int qq = 0; qq < 4; ++qq) {
                float zf = acc[T][qq] * s_f + h_f;
                float zc = acc[T + 4][qq] * s_c + h_c;
                float filt = 1.f / (1.f + __expf(-zf));
                pv[T][qq] = filt * softplus_f(zc);
            }
        }
#pragma unroll
        for (int T = 0; T < 4; ++T)
#pragma unroll
            for (int qq = 0; qq < 4; ++qq)
                p_s[(ebase + qq) * PLD + T * 16 + lo] = pv[T][qq];
        __syncthreads();
        for (int o = t; o < 256; o += 192) {
            int at = o >> 6, c = o & 63;
            float sv = 0.f;
#pragma unroll
            for (int m = 0; m < 12; ++m) sv += p_s[(at * 12 + m) * PLD + c];
            sout[(n0 + at) * FDIM + c] = sv;
            atomicAdd(&bn_s[c], sv);
            atomicAdd(&bn_s[64 + c], sv * sv);
        }
        __syncthreads();
        if (t < 128)
            atomicAdd(&bn2_slots[(blockIdx.x & 63) * 128 + t], bn_s[t]);
    }
}

// reduce 64 slots -> scale/shift; zero slots for next layer.
// bias (nullable): stats were accumulated WITHOUT the linear bias; mean shifts
// by bias, variance unchanged -> shift = beta - (mu_nob + b) * scale.
__global__ void k_bnfin(float* __restrict__ slots, const float* __restrict__ gamma,
                        const float* __restrict__ beta, const float* __restrict__ bias,
                        float* __restrict__ scale, float* __restrict__ shift,
                        float inv_cnt, int nc) {
    int c = threadIdx.x;
    if (c >= nc) return;
    float s1 = 0.f, s2 = 0.f;
    for (int s = 0; s < 64; ++s) {
        s1 += slots[s * 2 * nc + c];
        s2 += slots[s * 2 * nc + nc + c];
    }
    for (int s = 0; s < 64; ++s) {
        slots[s * 2 * nc + c] = 0.f;
        slots[s * 2 * nc + nc + c] = 0.f;
    }
    float mu_nob = s1 * inv_cnt;
    float var = fmaxf(s2 * inv_cnt - mu_nob * mu_nob, 0.f);
    float sc = gamma[c] * rsqrtf(var + EPSBN);
    float mu = mu_nob + (bias ? bias[c] : 0.f);
    scale[c] = sc;
    shift[c] = beta[c] - mu * sc;
}

// x = softplus(x + bn2(s)); also refresh xb
__global__ void k_x(float* __restrict__ x, __hip_bfloat16* __restrict__ xb,
                    const float* __restrict__ s,
                    const float* __restrict__ scale2, const float* __restrict__ shift2) {
    long i = (long)blockIdx.x * 256 + threadIdx.x;
    if (i >= (long)NATOM * FDIM) return;
    int c = (int)(i & 63);
    float v = softplus_f(x[i] + s[i] * scale2[c] + shift2[c]);
    x[i] = v;
    xb[i] = __float2bfloat16(v);
}

__global__ void k_pool(const float* __restrict__ x, const int* __restrict__ seg,
                       float* __restrict__ cry, float* __restrict__ cnt) {
    long i = (long)blockIdx.x * 256 + threadIdx.x;
    if (i >= (long)NATOM * FDIM) return;
    int n = (int)(i >> 6), c = (int)(i & 63);
    int cr = seg[n];
    atomicAdd(&cry[(long)cr * FDIM + c], x[i]);
    if (c == 0) atomicAdd(&cnt[cr], 1.f);
}

__global__ __launch_bounds__(256)
void k_head(const float* __restrict__ cry, const float* __restrict__ cnt,
            const float* __restrict__ fw, const float* __restrict__ fb,
            const float* __restrict__ hw, const float* __restrict__ hb,
            const float* __restrict__ ow, const float* __restrict__ ob,
            float* __restrict__ out) {
    __shared__ float cs[64], h1[128], red[256];
    int t = threadIdx.x, cr = blockIdx.x;
    if (t < 64) cs[t] = cry[(long)cr * 64 + t] / fmaxf(cnt[cr], 1.f);
    __syncthreads();
    if (t < 128) {
        float a = fb[t];
        for (int k = 0; k < 64; ++k) a += cs[k] * fw[k * 128 + t];
        h1[t] = fmaxf(a, 0.f);
    }
    __syncthreads();
    float a = hb[t];
    for (int k = 0; k < 128; ++k) a += h1[k] * hw[k * 256 + t];
    red[t] = a * ow[t];
    __syncthreads();
    for (int off = 128; off > 0; off >>= 1) {
        if (t < off) red[t] += red[t + off];
        __syncthreads();
    }
    if (t == 0) out[cr] = red[0] + ob[0];
}

extern "C" void kernel_launch(void* const* d_in, const int* in_sizes, int n_in,
                              void* d_out, int out_size, void* d_ws, size_t ws_size,
                              hipStream_t stream) {
    const float* atom_fea = (const float*)d_in[0];
    const float* nbr_fea  = (const float*)d_in[1];
    const int*   nbr_idx  = (const int*)d_in[2];
    const int*   seg      = (const int*)d_in[3];
    const float* emb_w    = (const float*)d_in[4];
    const float* emb_b    = (const float*)d_in[5];
    const float* conv_w   = (const float*)d_in[6];
    const float* conv_b   = (const float*)d_in[7];
    const float* bn1_g    = (const float*)d_in[8];
    const float* bn1_b    = (const float*)d_in[9];
    const float* bn2_g    = (const float*)d_in[10];
    const float* bn2_b    = (const float*)d_in[11];
    const float* fc_w     = (const float*)d_in[12];
    const float* fc_b     = (const float*)d_in[13];
    const float* head_w   = (const float*)d_in[14];
    const float* head_b   = (const float*)d_in[15];
    const float* out_w    = (const float*)d_in[16];
    const float* out_b    = (const float*)d_in[17];
    float* out = (float*)d_out;

    float* ws = (float*)d_ws;
    float* x = ws + X_OFF;
    __hip_bfloat16* xb   = (__hip_bfloat16*)(ws + XB_OFF);
    float* s = ws + S_OFF;
    __hip_bfloat16* nbrb = (__hip_bfloat16*)(ws + NBRB_OFF);
    __hip_bfloat16* ball = (__hip_bfloat16*)(ws + BALL_OFF);
    float* bn1s = ws + BN1S_OFF;
    float* bn2s = ws + BN2S_OFF;
    float* sc1 = ws + SC1_OFF;
    float* sh1 = ws + SH1_OFF;
    float* sc2 = ws + SC2_OFF;
    float* sh2 = ws + SH2_OFF;
    float* cry = ws + CRY_OFF;
    float* cnt = ws + CNT_OFF;

    k_zero<<<(int)((ZERO_CNT + 255) / 256), 256, 0, stream>>>(ws + ZERO_OFF, ZERO_CNT);
    k_nbrcvt<<<300000, 256, 0, stream>>>(nbr_fea, nbrb);
    k_embed<<<NATOM / 16, 256, 0, stream>>>(atom_fea, emb_w, emb_b, x, xb);

    for (int i = 0; i < 3; ++i) {
        const float* cw = conv_w + (long)i * 169 * C2;
        const float* cb = conv_b + (long)i * C2;
        k_bcvt<<<96, 256, 0, stream>>>(cw, ball);
        k_edge<0><<<NATOM / 4, 192, 0, stream>>>(xb, nbrb, ball, nbr_idx,
                                                 nullptr, nullptr, bn1s, nullptr, nullptr);
        k_bnfin<<<1, 128, 0, stream>>>(bn1s, bn1_g + i * C2, bn1_b + i * C2, cb,
                                       sc1, sh1, 1.f / 1200000.f, 128);
        k_edge<1><<<NATOM / 4, 192, 0, stream>>>(xb, nbrb, ball, nbr_idx,
                                                 sc1, sh1, nullptr, s, bn2s);
        k_bnfin<<<1, 64, 0, stream>>>(bn2s, bn2_g + i * 64, bn2_b + i * 64, nullptr,
                                      sc2, sh2, 1e-5f, 64);
        k_x<<<(NATOM * FDIM) / 256, 256, 0, stream>>>(x, xb, s, sc2, sh2);
    }

    k_pool<<<(NATOM * FDIM) / 256, 256, 0, stream>>>(x, seg, cry, cnt);
    k_head<<<2000, 256, 0, stream>>>(cry, cnt, fc_w, fc_b, head_w, head_b, out_w, out_b, out);
}

// Round 5
// 1979.390 us; speedup vs baseline: 1.5154x; 1.5154x over previous
//
#include <hip/hip_runtime.h>
#include <hip/hip_bf16.h>

#define NATOM 100000
#define MNBR  12
#define FDIM  64
#define BDIM  41
#define C2    128
#define EPSBN 1e-5f
#define NEDGE (NATOM * MNBR)   // 1,200,000
#define KP    64               // nbr K padded for MFMA (41 -> 64)
#define KALL  192              // x[n] (64) | x[j] (64) | nbr (64)
#define NFRAG 24576            // B frag-linear: 8 T * 6 kslice * 64 lane * 8 elem

typedef __attribute__((ext_vector_type(8))) short bf16x8;
typedef __attribute__((ext_vector_type(8))) unsigned short u16x8;
typedef __attribute__((ext_vector_type(4))) float f32x4;

// ---- ws layout (float units) ----
#define X_OFF    0L            // x: N*64 f32 (master)
#define XB_OFF   6400000L      // xb: N*64 bf16
#define S_OFF    9600000L      // nbr_sumed: N*64 f32
#define NBRB_OFF 16000000L     // nbr bf16 padded: 1.2M*64 bf16
#define BALL_OFF 54400000L     // B frag-linear bf16: 24576 elems
#define BN1S_OFF 54412288L     // 64 slots * 256
#define BN2S_OFF 54428672L     // 64 slots * 128
#define SC1_OFF  54436864L
#define SH1_OFF  54436992L
#define SC2_OFF  54437120L
#define SH2_OFF  54437184L
#define CRY_OFF  54437248L     // 2000*64
#define CNT_OFF  54565248L     // 2000
#define ZERO_OFF BN1S_OFF
#define ZERO_CNT 154960L

__device__ __forceinline__ float softplus_f(float v) {
    return fmaxf(v, 0.f) + __logf(1.f + __expf(-fabsf(v)));
}

__global__ void k_zero(float* __restrict__ p, long cnt) {
    long i = (long)blockIdx.x * 256 + threadIdx.x;
    if (i < cnt) p[i] = 0.f;
}

// nbr_fea f32 [1.2M][41] -> bf16 [1.2M][64] zero-padded
__global__ void k_nbrcvt(const float* __restrict__ nbr, __hip_bfloat16* __restrict__ outb) {
    long i = (long)blockIdx.x * 256 + threadIdx.x;
    if (i >= (long)NEDGE * KP) return;
    long e = i >> 6;
    int k = (int)(i & 63);
    float v = (k < BDIM) ? nbr[e * BDIM + k] : 0.f;
    outb[i] = __float2bfloat16(v);
}

// B in MFMA-fragment-linear layout: ballf[((T*6+s)*64 + lane)*8 + e]
// = W[k = s*32 + (lane>>4)*8 + e][col = T*16 + (lane&15)], rows 0..168 real.
__global__ void k_bcvt(const float* __restrict__ cw, __hip_bfloat16* __restrict__ ballf) {
    int i = blockIdx.x * 256 + threadIdx.x;
    if (i >= NFRAG) return;
    int T = i / 3072;
    int r = i - T * 3072;
    int s6 = r >> 9;
    int l = (r >> 3) & 63;
    int e = i & 7;
    int lo = l & 15, hi = l >> 4;
    int c = T * 16 + lo;
    int k = s6 * 32 + hi * 8 + e;
    float v = (k < 169) ? cw[k * C2 + c] : 0.f;
    ballf[i] = __float2bfloat16(v);
}

__global__ __launch_bounds__(256)
void k_embed(const float* __restrict__ af, const float* __restrict__ ew,
             const float* __restrict__ eb, float* __restrict__ x,
             __hip_bfloat16* __restrict__ xb) {
    int t = threadIdx.x;
    int c = t & 63, ag = t >> 6;
    long n0 = (long)blockIdx.x * 16 + ag * 4;
    float acc[4] = {0.f, 0.f, 0.f, 0.f};
    for (int k4 = 0; k4 < 23; ++k4) {
        float w0 = ew[(4 * k4 + 0) * FDIM + c];
        float w1 = ew[(4 * k4 + 1) * FDIM + c];
        float w2 = ew[(4 * k4 + 2) * FDIM + c];
        float w3 = ew[(4 * k4 + 3) * FDIM + c];
#pragma unroll
        for (int a = 0; a < 4; ++a) {
            const float4* ar = (const float4*)(af + (n0 + a) * 92);
            float4 v = ar[k4];
            acc[a] += v.x * w0 + v.y * w1 + v.z * w2 + v.w * w3;
        }
    }
    float b = eb[c];
#pragma unroll
    for (int a = 0; a < 4; ++a) {
        float v = acc[a] + b;
        x[(n0 + a) * FDIM + c] = v;
        xb[(n0 + a) * FDIM + c] = __float2bfloat16(v);
    }
}

// Edge kernel: one atom per 16x16 MFMA tile (12 real edge-rows + 4 zero rows),
// K=192 ([x[n] | x[j] | nbr]); B staged in LDS fragment-linear (conflict-free
// ds_read_b128); epilogue fully in-register via shfl reduce.
// APPLY=0: BN1 column stats. APPLY=1: BN1 apply + sigmoid*softplus + m-sum -> sout + BN2 stats.
// Block: 512 threads = 8 waves, each wave 4 atoms.
template <int APPLY>
__global__ __launch_bounds__(512, 2)
void k_edge(const __hip_bfloat16* __restrict__ xb,
            const __hip_bfloat16* __restrict__ nbrb,
            const __hip_bfloat16* __restrict__ ballf,
            const int* __restrict__ idxp,
            const float* __restrict__ sc1, const float* __restrict__ sh1,
            float* __restrict__ bn1_slots,
            float* __restrict__ sout, float* __restrict__ bn2_slots) {
    __shared__ __align__(16) short bfrag_s[NFRAG];   // 48 KiB
    __shared__ float bn_s[256];
    __shared__ float sc_s[128], sh_s[128];

    const int t = threadIdx.x;
    const int w = t >> 6, l = t & 63;
    const int lo = l & 15, hi = l >> 4;

    {
        const u16x8* src = (const u16x8*)ballf;
        u16x8* dst = (u16x8*)bfrag_s;
        for (int i = t; i < NFRAG / 8; i += 512) dst[i] = src[i];
    }
    if (t < 256) bn_s[t] = 0.f;
    if (APPLY && t < 128) { sc_s[t] = sc1[t]; sh_s[t] = sh1[t]; }
    __syncthreads();

    const bool real = lo < MNBR;
    const int atom0 = blockIdx.x * 32 + w * 4;

    for (int it = 0; it < 4; ++it) {
        const int atom = atom0 + it;
        const long e0 = (long)atom * MNBR;
        const long ei = real ? e0 + lo : e0;      // clamp pad lanes in-bounds
        const int j = real ? idxp[ei] : 0;

        const short* xn = (const short*)xb + (long)atom * FDIM + hi * 8;
        const short* xj = (const short*)xb + (long)j * FDIM + hi * 8;
        const short* nb = (const short*)nbrb + ei * KP + hi * 8;

        bf16x8 A[6];
        A[0] = *(const bf16x8*)(xn);
        A[1] = *(const bf16x8*)(xn + 32);
        A[2] = *(const bf16x8*)(xj);
        A[3] = *(const bf16x8*)(xj + 32);
        A[4] = *(const bf16x8*)(nb);
        A[5] = *(const bf16x8*)(nb + 32);
        if (!real) {
            bf16x8 zz;
#pragma unroll
            for (int u = 0; u < 8; ++u) zz[u] = 0;
#pragma unroll
            for (int u = 0; u < 6; ++u) A[u] = zz;
        }

        f32x4 acc[8];
#pragma unroll
        for (int T = 0; T < 8; ++T) {
            const bf16x8* bp = (const bf16x8*)bfrag_s + (T * 6) * 64 + l;
            f32x4 z = {0.f, 0.f, 0.f, 0.f};
#pragma unroll
            for (int s6 = 0; s6 < 6; ++s6) {
                bf16x8 B = bp[s6 * 64];
                z = __builtin_amdgcn_mfma_f32_16x16x32_bf16(A[s6], B, z, 0, 0, 0);
            }
            acc[T] = z;
        }
        // acc layout: col = T*16+lo, edge-row = hi*4+qq (rows 12..15 are zero pads)

        if (APPLY == 0) {
#pragma unroll
            for (int T = 0; T < 8; ++T) {
                float s1 = acc[T][0] + acc[T][1] + acc[T][2] + acc[T][3];
                float s2 = acc[T][0] * acc[T][0] + acc[T][1] * acc[T][1] +
                           acc[T][2] * acc[T][2] + acc[T][3] * acc[T][3];
                s1 += __shfl_xor(s1, 16); s2 += __shfl_xor(s2, 16);
                s1 += __shfl_xor(s1, 32); s2 += __shfl_xor(s2, 32);
                if (hi == 0) {
                    atomicAdd(&bn_s[T * 16 + lo], s1);
                    atomicAdd(&bn_s[128 + T * 16 + lo], s2);
                }
            }
        } else {
#pragma unroll
            for (int T = 0; T < 4; ++T) {
                const int c = T * 16 + lo;
                const float s_f = sc_s[c], h_f = sh_s[c];
                const float s_c = sc_s[64 + c], h_c = sh_s[64 + c];
                float pvsum = 0.f;
#pragma unroll
                for (int qq = 0; qq < 4; ++qq) {
                    float zf = acc[T][qq] * s_f + h_f;
                    float zc = acc[T + 4][qq] * s_c + h_c;
                    float filt = 1.f / (1.f + __expf(-zf));
                    pvsum += filt * softplus_f(zc);
                }
                if (hi == 3) pvsum = 0.f;   // pad rows 12..15: z=0 but BN shift != 0
                pvsum += __shfl_xor(pvsum, 16);
                pvsum += __shfl_xor(pvsum, 32);
                if (hi == 0) {
                    sout[(long)atom * FDIM + c] = pvsum;
                    atomicAdd(&bn_s[c], pvsum);
                    atomicAdd(&bn_s[64 + c], pvsum * pvsum);
                }
            }
        }
    }
    __syncthreads();
    if (APPLY == 0) {
        if (t < 256) atomicAdd(&bn1_slots[(blockIdx.x & 63) * 256 + t], bn_s[t]);
    } else {
        if (t < 128) atomicAdd(&bn2_slots[(blockIdx.x & 63) * 128 + t], bn_s[t]);
    }
}

// reduce 64 slots -> scale/shift; zero slots for next layer.
// NOTE: linear bias is a no-op under training-mode BN (output invariant to
// per-column constants) -> no bias term anywhere.
__global__ void k_bnfin(float* __restrict__ slots, const float* __restrict__ gamma,
                        const float* __restrict__ beta,
                        float* __restrict__ scale, float* __restrict__ shift,
                        float inv_cnt, int nc) {
    int c = threadIdx.x;
    if (c >= nc) return;
    float s1 = 0.f, s2 = 0.f;
    for (int s = 0; s < 64; ++s) {
        s1 += slots[s * 2 * nc + c];
        s2 += slots[s * 2 * nc + nc + c];
    }
    for (int s = 0; s < 64; ++s) {
        slots[s * 2 * nc + c] = 0.f;
        slots[s * 2 * nc + nc + c] = 0.f;
    }
    float mu = s1 * inv_cnt;
    float var = fmaxf(s2 * inv_cnt - mu * mu, 0.f);
    float sc = gamma[c] * rsqrtf(var + EPSBN);
    scale[c] = sc;
    shift[c] = beta[c] - mu * sc;
}

// x = softplus(x + bn2(s)); also refresh xb
__global__ void k_x(float* __restrict__ x, __hip_bfloat16* __restrict__ xb,
                    const float* __restrict__ s,
                    const float* __restrict__ scale2, const float* __restrict__ shift2) {
    long i = (long)blockIdx.x * 256 + threadIdx.x;
    if (i >= (long)NATOM * FDIM) return;
    int c = (int)(i & 63);
    float v = softplus_f(x[i] + s[i] * scale2[c] + shift2[c]);
    x[i] = v;
    xb[i] = __float2bfloat16(v);
}

__global__ void k_pool(const float* __restrict__ x, const int* __restrict__ seg,
                       float* __restrict__ cry, float* __restrict__ cnt) {
    long i = (long)blockIdx.x * 256 + threadIdx.x;
    if (i >= (long)NATOM * FDIM) return;
    int n = (int)(i >> 6), c = (int)(i & 63);
    int cr = seg[n];
    atomicAdd(&cry[(long)cr * FDIM + c], x[i]);
    if (c == 0) atomicAdd(&cnt[cr], 1.f);
}

__global__ __launch_bounds__(256)
void k_head(const float* __restrict__ cry, const float* __restrict__ cnt,
            const float* __restrict__ fw, const float* __restrict__ fb,
            const float* __restrict__ hw, const float* __restrict__ hb,
            const float* __restrict__ ow, const float* __restrict__ ob,
            float* __restrict__ out) {
    __shared__ float cs[64], h1[128], red[256];
    int t = threadIdx.x, cr = blockIdx.x;
    if (t < 64) cs[t] = cry[(long)cr * 64 + t] / fmaxf(cnt[cr], 1.f);
    __syncthreads();
    if (t < 128) {
        float a = fb[t];
        for (int k = 0; k < 64; ++k) a += cs[k] * fw[k * 128 + t];
        h1[t] = fmaxf(a, 0.f);
    }
    __syncthreads();
    float a = hb[t];
    for (int k = 0; k < 128; ++k) a += h1[k] * hw[k * 256 + t];
    red[t] = a * ow[t];
    __syncthreads();
    for (int off = 128; off > 0; off >>= 1) {
        if (t < off) red[t] += red[t + off];
        __syncthreads();
    }
    if (t == 0) out[cr] = red[0] + ob[0];
}

extern "C" void kernel_launch(void* const* d_in, const int* in_sizes, int n_in,
                              void* d_out, int out_size, void* d_ws, size_t ws_size,
                              hipStream_t stream) {
    const float* atom_fea = (const float*)d_in[0];
    const float* nbr_fea  = (const float*)d_in[1];
    const int*   nbr_idx  = (const int*)d_in[2];
    const int*   seg      = (const int*)d_in[3];
    const float* emb_w    = (const float*)d_in[4];
    const float* emb_b    = (const float*)d_in[5];
    const float* conv_w   = (const float*)d_in[6];
    const float* bn1_g    = (const float*)d_in[8];
    const float* bn1_b    = (const float*)d_in[9];
    const float* bn2_g    = (const float*)d_in[10];
    const float* bn2_b    = (const float*)d_in[11];
    const float* fc_w     = (const float*)d_in[12];
    const float* fc_b     = (const float*)d_in[13];
    const float* head_w   = (const float*)d_in[14];
    const float* head_b   = (const float*)d_in[15];
    const float* out_w    = (const float*)d_in[16];
    const float* out_b    = (const float*)d_in[17];
    float* out = (float*)d_out;

    float* ws = (float*)d_ws;
    float* x = ws + X_OFF;
    __hip_bfloat16* xb   = (__hip_bfloat16*)(ws + XB_OFF);
    float* s = ws + S_OFF;
    __hip_bfloat16* nbrb = (__hip_bfloat16*)(ws + NBRB_OFF);
    __hip_bfloat16* ballf = (__hip_bfloat16*)(ws + BALL_OFF);
    float* bn1s = ws + BN1S_OFF;
    float* bn2s = ws + BN2S_OFF;
    float* sc1 = ws + SC1_OFF;
    float* sh1 = ws + SH1_OFF;
    float* sc2 = ws + SC2_OFF;
    float* sh2 = ws + SH2_OFF;
    float* cry = ws + CRY_OFF;
    float* cnt = ws + CNT_OFF;

    k_zero<<<(int)((ZERO_CNT + 255) / 256), 256, 0, stream>>>(ws + ZERO_OFF, ZERO_CNT);
    k_nbrcvt<<<300000, 256, 0, stream>>>(nbr_fea, nbrb);
    k_embed<<<NATOM / 16, 256, 0, stream>>>(atom_fea, emb_w, emb_b, x, xb);

    for (int i = 0; i < 3; ++i) {
        const float* cw = conv_w + (long)i * 169 * C2;
        k_bcvt<<<96, 256, 0, stream>>>(cw, ballf);
        k_edge<0><<<NATOM / 32, 512, 0, stream>>>(xb, nbrb, ballf, nbr_idx,
                                                  nullptr, nullptr, bn1s, nullptr, nullptr);
        k_bnfin<<<1, 128, 0, stream>>>(bn1s, bn1_g + i * C2, bn1_b + i * C2,
                                       sc1, sh1, 1.f / 1200000.f, 128);
        k_edge<1><<<NATOM / 32, 512, 0, stream>>>(xb, nbrb, ballf, nbr_idx,
                                                  sc1, sh1, nullptr, s, bn2s);
        k_bnfin<<<1, 64, 0, stream>>>(bn2s, bn2_g + i * 64, bn2_b + i * 64,
                                      sc2, sh2, 1e-5f, 64);
        k_x<<<(NATOM * FDIM) / 256, 256, 0, stream>>>(x, xb, s, sc2, sh2);
    }

    k_pool<<<(NATOM * FDIM) / 256, 256, 0, stream>>>(x, seg, cry, cnt);
    k_head<<<2000, 256, 0, stream>>>(cry, cnt, fc_w, fc_b, head_w, head_b, out_w, out_b, out);
}

// Round 6
// 1559.650 us; speedup vs baseline: 1.9232x; 1.2691x over previous
//
#include <hip/hip_runtime.h>
#include <hip/hip_bf16.h>

#define NATOM 100000
#define MNBR  12
#define FDIM  64
#define BDIM  41
#define C2    128
#define EPSBN 1e-5f
#define NEDGE (NATOM * MNBR)   // 1,200,000
#define KP    64               // nbr K padded for MFMA (41 -> 64)
#define KALL  192              // x[n] (64) | x[j] (64) | nbr (64)
#define NFRAG 24576            // B frag-linear: 8 T * 6 kslice * 64 lane * 8 elem

typedef __attribute__((ext_vector_type(8))) short bf16x8;
typedef __attribute__((ext_vector_type(8))) unsigned short u16x8;
typedef __attribute__((ext_vector_type(4))) float f32x4;

// ---- ws layout (float units) ----
#define X_OFF    0L            // x: N*64 f32 (master)
#define XB_OFF   6400000L      // xb: N*64 bf16
#define S_OFF    9600000L      // nbr_sumed: N*64 f32
#define NBRB_OFF 16000000L     // nbr bf16 padded: 1.2M*64 bf16
#define BALL_OFF 54400000L     // B frag-linear bf16: 24576 elems
#define BN1S_OFF 54412288L     // 64 slots * 256
#define BN2S_OFF 54428672L     // 64 slots * 128
#define SC1_OFF  54436864L
#define SH1_OFF  54436992L
#define SC2_OFF  54437120L
#define SH2_OFF  54437184L
#define CRY_OFF  54437248L     // 2000*64
#define CNT_OFF  54565248L     // 2000
#define ZERO_OFF BN1S_OFF
#define ZERO_CNT 154960L

__device__ __forceinline__ float softplus_f(float v) {
    return fmaxf(v, 0.f) + __logf(1.f + __expf(-fabsf(v)));
}

__global__ void k_zero(float* __restrict__ p, long cnt) {
    long i = (long)blockIdx.x * 256 + threadIdx.x;
    if (i < cnt) p[i] = 0.f;
}

// nbr_fea f32 [1.2M][41] -> bf16 [1.2M][64] zero-padded
__global__ void k_nbrcvt(const float* __restrict__ nbr, __hip_bfloat16* __restrict__ outb) {
    long i = (long)blockIdx.x * 256 + threadIdx.x;
    if (i >= (long)NEDGE * KP) return;
    long e = i >> 6;
    int k = (int)(i & 63);
    float v = (k < BDIM) ? nbr[e * BDIM + k] : 0.f;
    outb[i] = __float2bfloat16(v);
}

// B in MFMA-fragment-linear layout: ballf[((T*6+s)*64 + lane)*8 + e]
// = W[k = s*32 + (lane>>4)*8 + e][col = T*16 + (lane&15)], rows 0..168 real.
__global__ void k_bcvt(const float* __restrict__ cw, __hip_bfloat16* __restrict__ ballf) {
    int i = blockIdx.x * 256 + threadIdx.x;
    if (i >= NFRAG) return;
    int T = i / 3072;
    int r = i - T * 3072;
    int s6 = r >> 9;
    int l = (r >> 3) & 63;
    int e = i & 7;
    int lo = l & 15, hi = l >> 4;
    int c = T * 16 + lo;
    int k = s6 * 32 + hi * 8 + e;
    float v = (k < 169) ? cw[k * C2 + c] : 0.f;
    ballf[i] = __float2bfloat16(v);
}

__global__ __launch_bounds__(256)
void k_embed(const float* __restrict__ af, const float* __restrict__ ew,
             const float* __restrict__ eb, float* __restrict__ x,
             __hip_bfloat16* __restrict__ xb) {
    int t = threadIdx.x;
    int c = t & 63, ag = t >> 6;
    long n0 = (long)blockIdx.x * 16 + ag * 4;
    float acc[4] = {0.f, 0.f, 0.f, 0.f};
    for (int k4 = 0; k4 < 23; ++k4) {
        float w0 = ew[(4 * k4 + 0) * FDIM + c];
        float w1 = ew[(4 * k4 + 1) * FDIM + c];
        float w2 = ew[(4 * k4 + 2) * FDIM + c];
        float w3 = ew[(4 * k4 + 3) * FDIM + c];
#pragma unroll
        for (int a = 0; a < 4; ++a) {
            const float4* ar = (const float4*)(af + (n0 + a) * 92);
            float4 v = ar[k4];
            acc[a] += v.x * w0 + v.y * w1 + v.z * w2 + v.w * w3;
        }
    }
    float b = eb[c];
#pragma unroll
    for (int a = 0; a < 4; ++a) {
        float v = acc[a] + b;
        x[(n0 + a) * FDIM + c] = v;
        xb[(n0 + a) * FDIM + c] = __float2bfloat16(v);
    }
}

// Edge kernel: one atom per 16x16 MFMA tile (12 real edge-rows + 4 pad rows,
// pads masked at epilogue), K=192 ([x[n] | x[j] | nbr]); B staged in LDS
// fragment-linear; A-gather double-buffered (prefetch atom it+1 before MFMAs
// of atom it). Block: 256 threads = 4 waves * 4 atoms = 16 atoms.
// APPLY=0: BN1 column stats. APPLY=1: BN1 apply + sig*softplus + m-sum + BN2 stats.
template <int APPLY>
__global__ __launch_bounds__(256, 3)
void k_edge(const __hip_bfloat16* __restrict__ xb,
            const __hip_bfloat16* __restrict__ nbrb,
            const __hip_bfloat16* __restrict__ ballf,
            const int* __restrict__ idxp,
            const float* __restrict__ sc1, const float* __restrict__ sh1,
            float* __restrict__ bn1_slots,
            float* __restrict__ sout, float* __restrict__ bn2_slots) {
    __shared__ __align__(16) short bfrag_s[NFRAG];   // 48 KiB
    __shared__ float bn_s[256];
    __shared__ float sc_s[128], sh_s[128];

    const int t = threadIdx.x;
    const int w = t >> 6, l = t & 63;
    const int lo = l & 15, hi = l >> 4;

    // stage B (L2-resident, coalesced, linear LDS)
    {
        const u16x8* src = (const u16x8*)ballf;
        u16x8* dst = (u16x8*)bfrag_s;
#pragma unroll
        for (int i = 0; i < 12; ++i) dst[i * 256 + t] = src[i * 256 + t];
    }
    bn_s[t] = 0.f;
    if (APPLY && t < 128) { sc_s[t] = sc1[t]; sh_s[t] = sh1[t]; }

    const bool real = lo < MNBR;
    const int elo = real ? lo : 0;           // clamp pad lanes in-bounds
    const int atom0 = blockIdx.x * 16 + w * 4;
    const short* xbS = (const short*)xb;
    const short* nbS = (const short*)nbrb;

    // prefetch all 4 neighbor indices (breaks idx->gather chain)
    int jj[4];
#pragma unroll
    for (int it = 0; it < 4; ++it)
        jj[it] = idxp[(long)(atom0 + it) * MNBR + elo];

    __syncthreads();   // B staged

#define LOADA(AR, IT) do {                                                     \
        const short* xn_ = xbS + (long)(atom0 + (IT)) * FDIM + hi * 8;         \
        const short* xj_ = xbS + (long)jj[IT] * FDIM + hi * 8;                 \
        const short* nb_ = nbS + ((long)(atom0 + (IT)) * MNBR + elo) * KP + hi * 8; \
        AR[0] = *(const bf16x8*)(xn_); AR[1] = *(const bf16x8*)(xn_ + 32);     \
        AR[2] = *(const bf16x8*)(xj_); AR[3] = *(const bf16x8*)(xj_ + 32);     \
        AR[4] = *(const bf16x8*)(nb_); AR[5] = *(const bf16x8*)(nb_ + 32);     \
    } while (0)

    bf16x8 A0[6], A1[6];
    LOADA(A0, 0);

#pragma unroll
    for (int it = 0; it < 4; ++it) {
        const int atom = atom0 + it;
        bf16x8* Ac = (it & 1) ? A1 : A0;
        bf16x8* An = (it & 1) ? A0 : A1;
        if (it == 0) LOADA(An, 1);
        else if (it == 1) LOADA(An, 2);
        else if (it == 2) LOADA(An, 3);

        f32x4 acc[8];
#pragma unroll
        for (int T = 0; T < 8; ++T) {
            const bf16x8* bp = (const bf16x8*)bfrag_s + T * 6 * 64 + l;
            f32x4 z = {0.f, 0.f, 0.f, 0.f};
#pragma unroll
            for (int s6 = 0; s6 < 6; ++s6)
                z = __builtin_amdgcn_mfma_f32_16x16x32_bf16(Ac[s6], bp[s6 * 64], z, 0, 0, 0);
            acc[T] = z;
        }
        // acc layout: col = T*16+lo, edge-row = hi*4+qq (rows 12..15 = pads, garbage)

        if (APPLY == 0) {
#pragma unroll
            for (int T = 0; T < 8; ++T) {
                float s1 = acc[T][0] + acc[T][1] + acc[T][2] + acc[T][3];
                float s2 = acc[T][0] * acc[T][0] + acc[T][1] * acc[T][1] +
                           acc[T][2] * acc[T][2] + acc[T][3] * acc[T][3];
                if (hi == 3) { s1 = 0.f; s2 = 0.f; }   // mask pad rows
                s1 += __shfl_xor(s1, 16); s2 += __shfl_xor(s2, 16);
                s1 += __shfl_xor(s1, 32); s2 += __shfl_xor(s2, 32);
                if (hi == 0) {
                    atomicAdd(&bn_s[T * 16 + lo], s1);
                    atomicAdd(&bn_s[128 + T * 16 + lo], s2);
                }
            }
        } else {
#pragma unroll
            for (int T = 0; T < 4; ++T) {
                const int c = T * 16 + lo;
                const float s_f = sc_s[c], h_f = sh_s[c];
                const float s_c = sc_s[64 + c], h_c = sh_s[64 + c];
                float pvsum = 0.f;
#pragma unroll
                for (int qq = 0; qq < 4; ++qq) {
                    float zf = acc[T][qq] * s_f + h_f;
                    float zc = acc[T + 4][qq] * s_c + h_c;
                    float filt = 1.f / (1.f + __expf(-zf));
                    pvsum += filt * softplus_f(zc);
                }
                if (hi == 3) pvsum = 0.f;   // mask pad rows
                pvsum += __shfl_xor(pvsum, 16);
                pvsum += __shfl_xor(pvsum, 32);
                if (hi == 0) {
                    sout[(long)atom * FDIM + c] = pvsum;
                    atomicAdd(&bn_s[c], pvsum);
                    atomicAdd(&bn_s[64 + c], pvsum * pvsum);
                }
            }
        }
    }
#undef LOADA

    __syncthreads();
    if (APPLY == 0) {
        atomicAdd(&bn1_slots[(blockIdx.x & 63) * 256 + t], bn_s[t]);
    } else {
        if (t < 128)
            atomicAdd(&bn2_slots[(blockIdx.x & 63) * 128 + t], bn_s[t]);
    }
}

// reduce 64 slots -> scale/shift; zero slots for next layer.
// NOTE: linear bias is a no-op under training-mode BN -> no bias anywhere.
__global__ void k_bnfin(float* __restrict__ slots, const float* __restrict__ gamma,
                        const float* __restrict__ beta,
                        float* __restrict__ scale, float* __restrict__ shift,
                        float inv_cnt, int nc) {
    int c = threadIdx.x;
    if (c >= nc) return;
    float s1 = 0.f, s2 = 0.f;
    for (int s = 0; s < 64; ++s) {
        s1 += slots[s * 2 * nc + c];
        s2 += slots[s * 2 * nc + nc + c];
    }
    for (int s = 0; s < 64; ++s) {
        slots[s * 2 * nc + c] = 0.f;
        slots[s * 2 * nc + nc + c] = 0.f;
    }
    float mu = s1 * inv_cnt;
    float var = fmaxf(s2 * inv_cnt - mu * mu, 0.f);
    float sc = gamma[c] * rsqrtf(var + EPSBN);
    scale[c] = sc;
    shift[c] = beta[c] - mu * sc;
}

// x = softplus(x + bn2(s)); also refresh xb
__global__ void k_x(float* __restrict__ x, __hip_bfloat16* __restrict__ xb,
                    const float* __restrict__ s,
                    const float* __restrict__ scale2, const float* __restrict__ shift2) {
    long i = (long)blockIdx.x * 256 + threadIdx.x;
    if (i >= (long)NATOM * FDIM) return;
    int c = (int)(i & 63);
    float v = softplus_f(x[i] + s[i] * scale2[c] + shift2[c]);
    x[i] = v;
    xb[i] = __float2bfloat16(v);
}

__global__ void k_pool(const float* __restrict__ x, const int* __restrict__ seg,
                       float* __restrict__ cry, float* __restrict__ cnt) {
    long i = (long)blockIdx.x * 256 + threadIdx.x;
    if (i >= (long)NATOM * FDIM) return;
    int n = (int)(i >> 6), c = (int)(i & 63);
    int cr = seg[n];
    atomicAdd(&cry[(long)cr * FDIM + c], x[i]);
    if (c == 0) atomicAdd(&cnt[cr], 1.f);
}

__global__ __launch_bounds__(256)
void k_head(const float* __restrict__ cry, const float* __restrict__ cnt,
            const float* __restrict__ fw, const float* __restrict__ fb,
            const float* __restrict__ hw, const float* __restrict__ hb,
            const float* __restrict__ ow, const float* __restrict__ ob,
            float* __restrict__ out) {
    __shared__ float cs[64], h1[128], red[256];
    int t = threadIdx.x, cr = blockIdx.x;
    if (t < 64) cs[t] = cry[(long)cr * 64 + t] / fmaxf(cnt[cr], 1.f);
    __syncthreads();
    if (t < 128) {
        float a = fb[t];
        for (int k = 0; k < 64; ++k) a += cs[k] * fw[k * 128 + t];
        h1[t] = fmaxf(a, 0.f);
    }
    __syncthreads();
    float a = hb[t];
    for (int k = 0; k < 128; ++k) a += h1[k] * hw[k * 256 + t];
    red[t] = a * ow[t];
    __syncthreads();
    for (int off = 128; off > 0; off >>= 1) {
        if (t < off) red[t] += red[t + off];
        __syncthreads();
    }
    if (t == 0) out[cr] = red[0] + ob[0];
}

extern "C" void kernel_launch(void* const* d_in, const int* in_sizes, int n_in,
                              void* d_out, int out_size, void* d_ws, size_t ws_size,
                              hipStream_t stream) {
    const float* atom_fea = (const float*)d_in[0];
    const float* nbr_fea  = (const float*)d_in[1];
    const int*   nbr_idx  = (const int*)d_in[2];
    const int*   seg      = (const int*)d_in[3];
    const float* emb_w    = (const float*)d_in[4];
    const float* emb_b    = (const float*)d_in[5];
    const float* conv_w   = (const float*)d_in[6];
    const float* bn1_g    = (const float*)d_in[8];
    const float* bn1_b    = (const float*)d_in[9];
    const float* bn2_g    = (const float*)d_in[10];
    const float* bn2_b    = (const float*)d_in[11];
    const float* fc_w     = (const float*)d_in[12];
    const float* fc_b     = (const float*)d_in[13];
    const float* head_w   = (const float*)d_in[14];
    const float* head_b   = (const float*)d_in[15];
    const float* out_w    = (const float*)d_in[16];
    const float* out_b    = (const float*)d_in[17];
    float* out = (float*)d_out;

    float* ws = (float*)d_ws;
    float* x = ws + X_OFF;
    __hip_bfloat16* xb   = (__hip_bfloat16*)(ws + XB_OFF);
    float* s = ws + S_OFF;
    __hip_bfloat16* nbrb = (__hip_bfloat16*)(ws + NBRB_OFF);
    __hip_bfloat16* ballf = (__hip_bfloat16*)(ws + BALL_OFF);
    float* bn1s = ws + BN1S_OFF;
    float* bn2s = ws + BN2S_OFF;
    float* sc1 = ws + SC1_OFF;
    float* sh1 = ws + SH1_OFF;
    float* sc2 = ws + SC2_OFF;
    float* sh2 = ws + SH2_OFF;
    float* cry = ws + CRY_OFF;
    float* cnt = ws + CNT_OFF;

    k_zero<<<(int)((ZERO_CNT + 255) / 256), 256, 0, stream>>>(ws + ZERO_OFF, ZERO_CNT);
    k_nbrcvt<<<300000, 256, 0, stream>>>(nbr_fea, nbrb);
    k_embed<<<NATOM / 16, 256, 0, stream>>>(atom_fea, emb_w, emb_b, x, xb);

    for (int i = 0; i < 3; ++i) {
        const float* cw = conv_w + (long)i * 169 * C2;
        k_bcvt<<<96, 256, 0, stream>>>(cw, ballf);
        k_edge<0><<<NATOM / 16, 256, 0, stream>>>(xb, nbrb, ballf, nbr_idx,
                                                  nullptr, nullptr, bn1s, nullptr, nullptr);
        k_bnfin<<<1, 128, 0, stream>>>(bn1s, bn1_g + i * C2, bn1_b + i * C2,
                                       sc1, sh1, 1.f / 1200000.f, 128);
        k_edge<1><<<NATOM / 16, 256, 0, stream>>>(xb, nbrb, ballf, nbr_idx,
                                                  sc1, sh1, nullptr, s, bn2s);
        k_bnfin<<<1, 64, 0, stream>>>(bn2s, bn2_g + i * 64, bn2_b + i * 64,
                                      sc2, sh2, 1e-5f, 64);
        k_x<<<(NATOM * FDIM) / 256, 256, 0, stream>>>(x, xb, s, sc2, sh2);
    }

    k_pool<<<(NATOM * FDIM) / 256, 256, 0, stream>>>(x, seg, cry, cnt);
    k_head<<<2000, 256, 0, stream>>>(cry, cnt, fc_w, fc_b, head_w, head_b, out_w, out_b, out);
}